// Round 2
// baseline (1151.237 us; speedup 1.0000x reference)
//
#include <hip/hip_runtime.h>

// RecallK: N=16384 points, D=128 fp32. recall@1 of nearest-neighbor labels.
// Strategy: tiled all-pairs dot products on the vector ALU (no fp32 MFMA on CDNA4),
// running per-row argmin of (sq_j - 2*dot)  [sq_i constant per row -> order-preserving],
// self-match excluded, first-min tie-break (strict <, ascending j, lexicographic reduce).
// R1 fix: labels are int32 (harness passes integer inputs as int, not int64).

#define NN 16384
#define DD 128
#define BI 128          // rows per block
#define BJ 128          // cols per tile
#define STRIDE 132      // LDS row stride in floats (pad: +4 keeps float4 writes aligned,
                        // inner-loop read banks = (4*tx + k) % 32 -> 2-way (free))
#define NTILES ((NN / 2) / BJ)  // 64 tiles per j-half

// --- kernel 1: per-row squared norms (one wave per row, coalesced float2) ---
__global__ __launch_bounds__(256) void sq_kernel(const float* __restrict__ feat,
                                                 float* __restrict__ sq) {
  int gid = blockIdx.x * 256 + threadIdx.x;
  int row = gid >> 6;
  int lane = threadIdx.x & 63;
  float2 v = reinterpret_cast<const float2*>(feat + (size_t)row * DD)[lane];
  float s = v.x * v.x + v.y * v.y;
#pragma unroll
  for (int off = 32; off > 0; off >>= 1) s += __shfl_xor(s, off, 64);
  if (lane == 0) sq[row] = s;
}

// --- kernel 2: main argmin over one j-half per block.y ---
// 256 threads = 16x16; thread (tx,ty) owns rows ty+16m, cols tx+16n (m,n in 0..7).
// Interleaved ownership spreads LDS banks (c multiple-of-8 ownership would 4-way conflict).
__global__ __launch_bounds__(256, 1) void nn_kernel(const float* __restrict__ feat,
                                                    const float* __restrict__ sq,
                                                    float* __restrict__ bestD,
                                                    int* __restrict__ bestI) {
  __shared__ float Alds[BI * STRIDE];  // 67.6 KB
  __shared__ float Blds[BJ * STRIDE];  // 67.6 KB  (total 132 KB -> 1 block/CU)
  const int rb = blockIdx.x;
  const int half = blockIdx.y;
  const int tid = threadIdx.x;
  const int tx = tid & 15;
  const int ty = tid >> 4;
  const int row0 = rb * BI;

  // stage A rows once (coalesced float4 reads; 8-way write conflict but once/block)
#pragma unroll
  for (int it = 0; it < 16; ++it) {
    int idx = it * 256 + tid;
    int kc = idx & 31;
    int r = idx >> 5;
    float4 v = reinterpret_cast<const float4*>(feat + (size_t)(row0 + r) * DD)[kc];
    *reinterpret_cast<float4*>(&Alds[r * STRIDE + kc * 4]) = v;
  }

  float best[8];
  int bidx[8];
#pragma unroll
  for (int m = 0; m < 8; ++m) {
    best[m] = 3.4e38f;
    bidx[m] = 0;
  }

  for (int t = 0; t < NTILES; ++t) {
    const int jb = half * (NN / 2) + t * BJ;
    __syncthreads();  // previous tile's readers done before overwrite
#pragma unroll
    for (int it = 0; it < 16; ++it) {
      int idx = it * 256 + tid;
      int kc = idx & 31;
      int c = idx >> 5;
      float4 v = reinterpret_cast<const float4*>(feat + (size_t)(jb + c) * DD)[kc];
      *reinterpret_cast<float4*>(&Blds[c * STRIDE + kc * 4]) = v;
    }
    __syncthreads();

    float acc[8][8];
#pragma unroll
    for (int m = 0; m < 8; ++m)
#pragma unroll
      for (int n = 0; n < 8; ++n) acc[m][n] = 0.f;

#pragma unroll 8
    for (int k = 0; k < DD; ++k) {
      float a[8], b[8];
#pragma unroll
      for (int m = 0; m < 8; ++m) a[m] = Alds[(ty + 16 * m) * STRIDE + k];
#pragma unroll
      for (int n = 0; n < 8; ++n) b[n] = Blds[(tx + 16 * n) * STRIDE + k];
#pragma unroll
      for (int m = 0; m < 8; ++m)
#pragma unroll
        for (int n = 0; n < 8; ++n) acc[m][n] = fmaf(a[m], b[n], acc[m][n]);
    }

    // epilogue: v = sq_j - 2*dot; strict < keeps earliest j (ascending n, ascending t)
#pragma unroll
    for (int n = 0; n < 8; ++n) {
      int j = jb + tx + 16 * n;
      float sj = sq[j];
#pragma unroll
      for (int m = 0; m < 8; ++m) {
        float v = fmaf(-2.f, acc[m][n], sj);
        int ig = row0 + ty + 16 * m;
        if (j != ig && v < best[m]) {
          best[m] = v;
          bidx[m] = j;
        }
      }
    }
  }

  // cross-thread (tx) reduce per row; lexicographic (d, j) matches argmin-first
  __syncthreads();
  float* redD = Alds;                       // reuse: [128][16]
  int* redI = reinterpret_cast<int*>(Blds); // reuse: [128][16]
#pragma unroll
  for (int m = 0; m < 8; ++m) {
    int r = ty + 16 * m;
    redD[r * 16 + tx] = best[m];
    redI[r * 16 + tx] = bidx[m];
  }
  __syncthreads();
  if (tid < BI) {
    float bd = redD[tid * 16];
    int bj = redI[tid * 16];
#pragma unroll
    for (int x = 1; x < 16; ++x) {
      float d = redD[tid * 16 + x];
      int j = redI[tid * 16 + x];
      if (d < bd || (d == bd && j < bj)) {
        bd = d;
        bj = j;
      }
    }
    bestD[half * NN + row0 + tid] = bd;
    bestI[half * NN + row0 + tid] = bj;
  }
}

// --- kernel 3: merge halves, count label matches (int atomics -> deterministic) ---
__global__ __launch_bounds__(256) void combine_kernel(const float* __restrict__ bestD,
                                                      const int* __restrict__ bestI,
                                                      const int* __restrict__ labels,
                                                      int* __restrict__ count) {
  int r = blockIdx.x * 256 + threadIdx.x;
  float d0 = bestD[r];
  int i0 = bestI[r];
  float d1 = bestD[NN + r];
  int i1 = bestI[NN + r];
  int pred = (d1 < d0) ? i1 : i0;  // tie -> half 0 (smaller indices) = argmin-first
  bool match = (labels[pred] == labels[r]);
  unsigned long long mb = __ballot(match);
  if ((threadIdx.x & 63) == 0) atomicAdd(count, (int)__popcll(mb));
}

__global__ void finalize_kernel(const int* __restrict__ count, float* __restrict__ out) {
  out[0] = (float)(*count) * (1.0f / 16384.0f);
}

extern "C" void kernel_launch(void* const* d_in, const int* in_sizes, int n_in,
                              void* d_out, int out_size, void* d_ws, size_t ws_size,
                              hipStream_t stream) {
  const float* feat = (const float*)d_in[0];
  const int* labels = (const int*)d_in[1];
  float* out = (float*)d_out;
  char* ws = (char*)d_ws;

  int* count = (int*)ws;                              // 4 B
  float* sq = (float*)(ws + 256);                     // 64 KB
  float* bestD = (float*)(ws + 256 + 65536);          // 2*N floats = 128 KB
  int* bestI = (int*)(ws + 256 + 65536 + 131072);     // 2*N ints  = 128 KB
  // total ws use ~320 KB

  hipMemsetAsync(count, 0, sizeof(int), stream);
  sq_kernel<<<NN / 4, 256, 0, stream>>>(feat, sq);
  nn_kernel<<<dim3(NN / BI, 2), 256, 0, stream>>>(feat, sq, bestD, bestI);
  combine_kernel<<<NN / 256, 256, 0, stream>>>(bestD, bestI, labels, count);
  finalize_kernel<<<1, 1, 0, stream>>>(count, out);
}

// Round 5
// 295.354 us; speedup vs baseline: 3.8978x; 3.8978x over previous
//
#include <hip/hip_runtime.h>

// RecallK via bf16 hi/lo split on matrix cores.
// dot(x_i,x_j) = hi.hi + hi.lo + lo.hi + lo.lo  (full product: dot error ~ fp32-accum only).
// argmin_j (sq_j - 2*dot) per row == argmin of ref distmat (row-constant sq_i dropped).
// R5 fix: waves (wrow,0) and (wrow,1) each scan only their wcol's half of the columns
// but previously BOTH wrote bestD[row] (same rows!) -> write race, min over half the
// candidates (caused R3 tripwire nondeterminism AND R4's chance-level result).
// Now each wave posts its per-row (d,j) to LDS Md/Mi[wcol][128]; one lexicographic
// merge after __syncthreads writes each row exactly once.
// P layout (A and B frags of mfma_f32_32x32x16_bf16 read lane-linear 16B chunks):
//   chunk(g,ks,kh,c) = ((g*8+ks)*2+kh)*32 + c   holds  X[g*32+c][ks*16+kh*8 .. +8]
//   frag lane l -> kh = l>>5, c = l&31 -> lds/global addr = base + l*16 (conflict-free)
//   (any within-instruction k-permutation is shared by A and B frags -> cancels in A.B)

typedef __bf16 bf16x8 __attribute__((ext_vector_type(8)));
typedef float f32x16 __attribute__((ext_vector_type(16)));

#define NN 16384
#define MFMA(A, B, C) __builtin_amdgcn_mfma_f32_32x32x16_bf16(A, B, C, 0, 0, 0)
#define GLDS(gsrc, ldst)                                                              \
  __builtin_amdgcn_global_load_lds((const __attribute__((address_space(1))) void*)(gsrc), \
                                   (__attribute__((address_space(3))) void*)(ldst), 16, 0, 0)

// --- per-row squared norms, exact fp32 (one wave per row) ---
__global__ __launch_bounds__(256) void sq_kernel(const float* __restrict__ feat,
                                                 float* __restrict__ sq) {
  int gid = blockIdx.x * 256 + threadIdx.x;
  int row = gid >> 6;
  int lane = threadIdx.x & 63;
  float2 v = reinterpret_cast<const float2*>(feat + (size_t)row * 128)[lane];
  float s = v.x * v.x + v.y * v.y;
#pragma unroll
  for (int off = 32; off > 0; off >>= 1) s += __shfl_xor(s, off, 64);
  if (lane == 0) sq[row] = s;
}

// --- fp32 -> (hi,lo) bf16 banks in MFMA-chunk-permuted order ---
__global__ __launch_bounds__(256) void convert_kernel(const float* __restrict__ feat,
                                                      bf16x8* __restrict__ Ph,
                                                      bf16x8* __restrict__ Pl) {
  int chunk = blockIdx.x * 256 + threadIdx.x;  // 262144 chunks
  int c = chunk & 31;
  int kh = (chunk >> 5) & 1;
  int ks = (chunk >> 6) & 7;
  int g = chunk >> 9;
  int row = g * 32 + c;
  int k0 = ks * 16 + kh * 8;
  const float4* s = reinterpret_cast<const float4*>(feat + (size_t)row * 128 + k0);
  float4 v0 = s[0], v1 = s[1];
  float xs[8] = {v0.x, v0.y, v0.z, v0.w, v1.x, v1.y, v1.z, v1.w};
  bf16x8 hv, lv;
#pragma unroll
  for (int e = 0; e < 8; ++e) {
    float x = xs[e];
    __bf16 h = (__bf16)x;
    hv[e] = h;
    lv[e] = (__bf16)(x - (float)h);
  }
  Ph[chunk] = hv;
  Pl[chunk] = lv;
}

// --- main: 256 blocks (128 row-panels x 2 j-halves), 4 waves, wave-tile 64x64 ---
__global__ __launch_bounds__(256, 1) void nn_mfma(const bf16x8* __restrict__ Ph,
                                                  const bf16x8* __restrict__ Pl,
                                                  const float* __restrict__ sq,
                                                  float* __restrict__ bestD,
                                                  int* __restrict__ bestI) {
  __shared__ bf16x8 BhL[2][2048];  // 2 x 32 KB
  __shared__ bf16x8 BlL[2][2048];  // 2 x 32 KB
  __shared__ float Md[2][128];     // per-wcol per-row argmin candidates
  __shared__ int Mi[2][128];       // total LDS 133120 B -> 1 block/CU
  const int bid = blockIdx.x;
  const int xcd = bid & 7;                       // group same-half blocks per XCD:
  const int half = xcd >> 2;                     // each XCD streams one 4 MB B-half (L2-fit)
  const int panel = (xcd & 3) * 32 + (bid >> 3); // bijective over 128 panels x 2 halves
  const int tid = threadIdx.x;
  const int w = tid >> 6;        // wave 0..3
  const int lane = tid & 63;
  const int wrow = w >> 1, wcol = w & 1;
  const int laneh = lane >> 5, lanec = lane & 31;

  // A panel (64 rows x K=128, hi+lo) into registers: 32 frags = 128 VGPR
  bf16x8 Ah0[8], Ah1[8], Al0[8], Al1[8];
  {
    int g0 = panel * 4 + wrow * 2;
#pragma unroll
    for (int ks = 0; ks < 8; ++ks) {
      int ch0 = ((g0 * 8 + ks) * 2 + laneh) * 32 + lanec;
      int ch1 = (((g0 + 1) * 8 + ks) * 2 + laneh) * 32 + lanec;
      Ah0[ks] = Ph[ch0];  Al0[ks] = Pl[ch0];
      Ah1[ks] = Ph[ch1];  Al1[ks] = Pl[ch1];
    }
  }

  // stage one 128-col B tile (hi+lo) into LDS buffer `nbuf`; wave w owns col-group w
  auto stage = [&](int nbuf, int tt) {
    int gj = half * 256 + tt * 4 + w;
#pragma unroll
    for (int ks = 0; ks < 8; ++ks) {
      size_t srcoff = ((size_t)((gj * 8 + ks) * 64 + lane)) * 16;
      GLDS((const char*)Ph + srcoff, &BhL[nbuf][(w * 8 + ks) * 64]);
      GLDS((const char*)Pl + srcoff, &BlL[nbuf][(w * 8 + ks) * 64]);
    }
  };

  float bD0[16], bD1[16];
  int bI0[16], bI1[16];
#pragma unroll
  for (int r = 0; r < 16; ++r) {
    bD0[r] = 3.4e38f; bD1[r] = 3.4e38f;
    bI0[r] = 0; bI1[r] = 0;
  }

  stage(0, 0);
  __syncthreads();  // full fence: stage complete + all waves synced

  int buf = 0;
  const int igbase = panel * 128 + wrow * 64 + 4 * laneh;

  for (int t = 0; t < 64; ++t) {
    const int jb = half * 8192 + t * 128;
    const int j0 = jb + wcol * 64 + lanec;
    const int j1 = j0 + 32;
    float sq0 = sq[j0];   // issued before stage: compiler wait = counted vmcnt,
    float sq1 = sq[j1];   // leaves the 32 staging loads in flight under MFMA
    if (t < 63) stage(buf ^ 1, t + 1);

    f32x16 a00 = {}, a01 = {}, a10 = {}, a11 = {};
    const int cg0 = (wcol * 2) * 8, cg1 = (wcol * 2 + 1) * 8;
#pragma unroll
    for (int ks = 0; ks < 8; ++ks) {
      bf16x8 b0h = BhL[buf][(cg0 + ks) * 64 + lane];
      bf16x8 b0l = BlL[buf][(cg0 + ks) * 64 + lane];
      bf16x8 b1h = BhL[buf][(cg1 + ks) * 64 + lane];
      bf16x8 b1l = BlL[buf][(cg1 + ks) * 64 + lane];
      a00 = MFMA(Ah0[ks], b0h, a00);
      a00 = MFMA(Al0[ks], b0h, a00);
      a00 = MFMA(Ah0[ks], b0l, a00);
      a00 = MFMA(Al0[ks], b0l, a00);
      a10 = MFMA(Ah1[ks], b0h, a10);
      a10 = MFMA(Al1[ks], b0h, a10);
      a10 = MFMA(Ah1[ks], b0l, a10);
      a10 = MFMA(Al1[ks], b0l, a10);
      a01 = MFMA(Ah0[ks], b1h, a01);
      a01 = MFMA(Al0[ks], b1h, a01);
      a01 = MFMA(Ah0[ks], b1l, a01);
      a01 = MFMA(Al0[ks], b1l, a01);
      a11 = MFMA(Ah1[ks], b1h, a11);
      a11 = MFMA(Al1[ks], b1h, a11);
      a11 = MFMA(Al1[ks], b1l, a11);
      a11 = MFMA(Ah1[ks], b1l, a11);
    }

    // epilogue: d = sq_j - 2*dot; j0 (< j1) first; cross-wcol order fixed at final merge
#pragma unroll
    for (int r = 0; r < 16; ++r) {
      int rb = (r & 3) + 8 * (r >> 2);
      {
        float d = fmaf(-2.0f, a00[r], sq0);
        int ig = igbase + rb;
        if (j0 != ig && d < bD0[r]) { bD0[r] = d; bI0[r] = j0; }
      }
      {
        float d = fmaf(-2.0f, a10[r], sq0);
        int ig = igbase + 32 + rb;
        if (j0 != ig && d < bD1[r]) { bD1[r] = d; bI1[r] = j0; }
      }
      {
        float d = fmaf(-2.0f, a01[r], sq1);
        int ig = igbase + rb;
        if (j1 != ig && d < bD0[r]) { bD0[r] = d; bI0[r] = j1; }
      }
      {
        float d = fmaf(-2.0f, a11[r], sq1);
        int ig = igbase + 32 + rb;
        if (j1 != ig && d < bD1[r]) { bD1[r] = d; bI1[r] = j1; }
      }
    }

    __syncthreads();  // drains my stage (vmcnt 0) + all waves done reading buf
    buf ^= 1;
  }

  // cross-lane argmin (32 col-lanes share each row); lexicographic (d, j) = first-min
#pragma unroll
  for (int r = 0; r < 16; ++r) {
    float d0 = bD0[r], d1 = bD1[r];
    int i0 = bI0[r], i1 = bI1[r];
#pragma unroll
    for (int off = 1; off < 32; off <<= 1) {
      float od = __shfl_xor(d0, off); int oi = __shfl_xor(i0, off);
      if (od < d0 || (od == d0 && oi < i0)) { d0 = od; i0 = oi; }
      od = __shfl_xor(d1, off); oi = __shfl_xor(i1, off);
      if (od < d1 || (od == d1 && oi < i1)) { d1 = od; i1 = oi; }
    }
    // post per-wave result to LDS; rows are shared between wcol=0 and wcol=1 waves
    if (lanec == 0) {
      int lr = wrow * 64 + 4 * laneh + ((r & 3) + 8 * (r >> 2));
      Md[wcol][lr] = d0;      Mi[wcol][lr] = i0;
      Md[wcol][lr + 32] = d1; Mi[wcol][lr + 32] = i1;
    }
  }
  __syncthreads();
  // final cross-wcol merge: each of the 128 block rows written exactly once
  if (tid < 128) {
    float da = Md[0][tid]; int ia = Mi[0][tid];
    float db = Md[1][tid]; int ib = Mi[1][tid];
    if (db < da || (db == da && ib < ia)) { da = db; ia = ib; }
    bestD[half * NN + panel * 128 + tid] = da;
    bestI[half * NN + panel * 128 + tid] = ia;
  }
}

// --- merge halves, count label matches ---
__global__ __launch_bounds__(256) void combine_kernel(const float* __restrict__ bestD,
                                                      const int* __restrict__ bestI,
                                                      const int* __restrict__ labels,
                                                      int* __restrict__ count) {
  int r = blockIdx.x * 256 + threadIdx.x;
  float d0 = bestD[r];
  int i0 = bestI[r];
  float d1 = bestD[NN + r];
  int i1 = bestI[NN + r];
  int pred = (d1 < d0) ? i1 : i0;  // tie -> half 0 (smaller j) = argmin-first
  bool match = (labels[pred] == labels[r]);
  unsigned long long mb = __ballot(match);
  if ((threadIdx.x & 63) == 0) atomicAdd(count, (int)__popcll(mb));
}

__global__ void finalize_kernel(const int* __restrict__ count, float* __restrict__ out) {
  out[0] = (float)(*count) * (1.0f / 16384.0f);
}

extern "C" void kernel_launch(void* const* d_in, const int* in_sizes, int n_in,
                              void* d_out, int out_size, void* d_ws, size_t ws_size,
                              hipStream_t stream) {
  const float* feat = (const float*)d_in[0];
  const int* labels = (const int*)d_in[1];
  float* out = (float*)d_out;
  char* ws = (char*)d_ws;

  int* count = (int*)ws;                                  // 4 B
  float* sq = (float*)(ws + 1024);                        // 64 KB
  float* bestD = (float*)(ws + 1024 + 65536);             // 128 KB
  int* bestI = (int*)(ws + 1024 + 65536 + 131072);        // 128 KB
  bf16x8* Ph = (bf16x8*)(ws + (1 << 20));                 // 4 MB
  bf16x8* Pl = (bf16x8*)(ws + (6 << 20));                 // 4 MB   (total ~10 MB)

  hipMemsetAsync(count, 0, sizeof(int), stream);
  sq_kernel<<<NN / 4, 256, 0, stream>>>(feat, sq);
  convert_kernel<<<1024, 256, 0, stream>>>(feat, Ph, Pl);
  nn_mfma<<<256, 256, 0, stream>>>(Ph, Pl, sq, bestD, bestI);
  combine_kernel<<<NN / 256, 256, 0, stream>>>(bestD, bestI, labels, count);
  finalize_kernel<<<1, 1, 0, stream>>>(count, out);
}

// Round 6
// 272.962 us; speedup vs baseline: 4.2176x; 1.0820x over previous
//
#include <hip/hip_runtime.h>

// RecallK via bf16 hi/lo split on matrix cores.
// dot(x_i,x_j) = hi.hi + hi.lo + lo.hi + lo.lo  (full product: dot error ~ fp32-accum only).
// argmin_j (sq_j - 2*dot) per row == argmin of ref distmat (row-constant sq_i dropped).
// R6: occupancy fix. R5 measured MfmaUtil 35% == exactly the 109us MFMA floor / 330us:
// at 1 wave/SIMD the wave's in-order epilogue+ds_reads serialize with MFMA issue.
// Now 8 waves x 512 threads (wave-tile 32x64), launch_bounds(512,2) -> VGPR<=256 ->
// 2 waves/SIMD: one wave's VALU/LDS phases overlap the other's MFMA (m114).
// P layout (A and B frags of mfma_f32_32x32x16_bf16 read lane-linear 16B chunks):
//   chunk(g,ks,kh,c) = ((g*8+ks)*2+kh)*32 + c   holds  X[g*32+c][ks*16+kh*8 .. +8]
//   frag lane l -> kh = l>>5, c = l&31 -> lds/global addr = base + l*16 (conflict-free)

typedef __bf16 bf16x8 __attribute__((ext_vector_type(8)));
typedef float f32x16 __attribute__((ext_vector_type(16)));

#define NN 16384
#define MFMA(A, B, C) __builtin_amdgcn_mfma_f32_32x32x16_bf16(A, B, C, 0, 0, 0)
#define GLDS(gsrc, ldst)                                                              \
  __builtin_amdgcn_global_load_lds((const __attribute__((address_space(1))) void*)(gsrc), \
                                   (__attribute__((address_space(3))) void*)(ldst), 16, 0, 0)

// --- per-row squared norms, exact fp32 (one wave per row) ---
__global__ __launch_bounds__(256) void sq_kernel(const float* __restrict__ feat,
                                                 float* __restrict__ sq) {
  int gid = blockIdx.x * 256 + threadIdx.x;
  int row = gid >> 6;
  int lane = threadIdx.x & 63;
  float2 v = reinterpret_cast<const float2*>(feat + (size_t)row * 128)[lane];
  float s = v.x * v.x + v.y * v.y;
#pragma unroll
  for (int off = 32; off > 0; off >>= 1) s += __shfl_xor(s, off, 64);
  if (lane == 0) sq[row] = s;
}

// --- fp32 -> (hi,lo) bf16 banks in MFMA-chunk-permuted order ---
__global__ __launch_bounds__(256) void convert_kernel(const float* __restrict__ feat,
                                                      bf16x8* __restrict__ Ph,
                                                      bf16x8* __restrict__ Pl) {
  int chunk = blockIdx.x * 256 + threadIdx.x;  // 262144 chunks
  int c = chunk & 31;
  int kh = (chunk >> 5) & 1;
  int ks = (chunk >> 6) & 7;
  int g = chunk >> 9;
  int row = g * 32 + c;
  int k0 = ks * 16 + kh * 8;
  const float4* s = reinterpret_cast<const float4*>(feat + (size_t)row * 128 + k0);
  float4 v0 = s[0], v1 = s[1];
  float xs[8] = {v0.x, v0.y, v0.z, v0.w, v1.x, v1.y, v1.z, v1.w};
  bf16x8 hv, lv;
#pragma unroll
  for (int e = 0; e < 8; ++e) {
    float x = xs[e];
    __bf16 h = (__bf16)x;
    hv[e] = h;
    lv[e] = (__bf16)(x - (float)h);
  }
  Ph[chunk] = hv;
  Pl[chunk] = lv;
}

// --- main: 256 blocks (128 row-panels x 2 j-halves), 8 waves, wave-tile 32x64 ---
__global__ __launch_bounds__(512, 2) void nn_mfma(const bf16x8* __restrict__ Ph,
                                                  const bf16x8* __restrict__ Pl,
                                                  const float* __restrict__ sq,
                                                  float* __restrict__ bestD,
                                                  int* __restrict__ bestI) {
  __shared__ bf16x8 BhL[2][2048];  // 2 x 32 KB
  __shared__ bf16x8 BlL[2][2048];  // 2 x 32 KB
  __shared__ float Md[2][128];     // per-wcol per-row argmin candidates
  __shared__ int Mi[2][128];       // total LDS ~133 KB -> 1 block/CU (8 waves = 2/SIMD)
  const int bid = blockIdx.x;
  const int xcd = bid & 7;                       // group same-half blocks per XCD:
  const int half = xcd >> 2;                     // each XCD streams one 4 MB B-half (L2-fit)
  const int panel = (xcd & 3) * 32 + (bid >> 3); // bijective over 128 panels x 2 halves
  const int tid = threadIdx.x;
  const int w = tid >> 6;        // wave 0..7
  const int lane = tid & 63;
  const int wrow = w >> 1, wcol = w & 1;
  const int laneh = lane >> 5, lanec = lane & 31;

  // A row-group (32 rows x K=128, hi+lo) into registers: 16 frags = 64 VGPR
  bf16x8 Ah[8], Al[8];
  {
    int g = panel * 4 + wrow;
#pragma unroll
    for (int ks = 0; ks < 8; ++ks) {
      int ch = ((g * 8 + ks) * 2 + laneh) * 32 + lanec;
      Ah[ks] = Ph[ch];
      Al[ks] = Pl[ch];
    }
  }

  // stage one 128-col B tile (hi+lo) into LDS buffer `nbuf`:
  // wave w stages (w&1 ? lo : hi) bank of col-group w>>1  (8 GLDS per wave)
  auto stage = [&](int nbuf, int tt) {
    const int cg = w >> 1;
    const int gj = half * 256 + tt * 4 + cg;
    const bf16x8* src = (w & 1) ? Pl : Ph;
    bf16x8* dst = (w & 1) ? &BlL[nbuf][cg * 512] : &BhL[nbuf][cg * 512];
#pragma unroll
    for (int ks = 0; ks < 8; ++ks) {
      size_t srcoff = ((size_t)((gj * 8 + ks) * 64 + lane)) * 16;
      GLDS((const char*)src + srcoff, dst + ks * 64);
    }
  };

  float bD0[16], bD1[16];
  int bI0[16], bI1[16];
#pragma unroll
  for (int r = 0; r < 16; ++r) {
    bD0[r] = 3.4e38f; bD1[r] = 3.4e38f;
    bI0[r] = 0; bI1[r] = 0;
  }

  stage(0, 0);
  __syncthreads();  // full fence: stage complete + all waves synced

  int buf = 0;
  const int igbase = panel * 128 + wrow * 32 + 4 * laneh;

  for (int t = 0; t < 64; ++t) {
    const int jb = half * 8192 + t * 128;
    const int j0 = jb + wcol * 64 + lanec;
    const int j1 = j0 + 32;
    float sq0 = sq[j0];   // issued before stage: compiler wait = counted vmcnt,
    float sq1 = sq[j1];   // leaves the staging loads in flight under MFMA
    if (t < 63) stage(buf ^ 1, t + 1);

    f32x16 a0 = {}, a1 = {};
    const int cg0 = wcol * 2, cg1 = wcol * 2 + 1;
#pragma unroll
    for (int ks = 0; ks < 8; ++ks) {
      bf16x8 b0h = BhL[buf][(cg0 * 8 + ks) * 64 + lane];
      bf16x8 b0l = BlL[buf][(cg0 * 8 + ks) * 64 + lane];
      bf16x8 b1h = BhL[buf][(cg1 * 8 + ks) * 64 + lane];
      bf16x8 b1l = BlL[buf][(cg1 * 8 + ks) * 64 + lane];
      a0 = MFMA(Ah[ks], b0h, a0);
      a0 = MFMA(Al[ks], b0h, a0);
      a0 = MFMA(Ah[ks], b0l, a0);
      a0 = MFMA(Al[ks], b0l, a0);
      a1 = MFMA(Ah[ks], b1h, a1);
      a1 = MFMA(Al[ks], b1h, a1);
      a1 = MFMA(Ah[ks], b1l, a1);
      a1 = MFMA(Al[ks], b1l, a1);
    }

    // epilogue: d = sq_j - 2*dot; strict < + ascending t keeps earliest j per array;
    // cross-array / cross-wcol ordering fixed at the final lexicographic merges
#pragma unroll
    for (int r = 0; r < 16; ++r) {
      int rb = (r & 3) + 8 * (r >> 2);
      int ig = igbase + rb;
      {
        float d = fmaf(-2.0f, a0[r], sq0);
        if (j0 != ig && d < bD0[r]) { bD0[r] = d; bI0[r] = j0; }
      }
      {
        float d = fmaf(-2.0f, a1[r], sq1);
        if (j1 != ig && d < bD1[r]) { bD1[r] = d; bI1[r] = j1; }
      }
    }

    __syncthreads();  // drains my stage (vmcnt 0) + all waves done reading buf
    buf ^= 1;
  }

  // merge the two col-sets, then cross-lane argmin over the 32 lanec lanes;
  // lexicographic (d, j) everywhere = numpy first-min
#pragma unroll
  for (int r = 0; r < 16; ++r) {
    float d0 = bD0[r];
    int i0 = bI0[r];
    if (bD1[r] < d0 || (bD1[r] == d0 && bI1[r] < i0)) { d0 = bD1[r]; i0 = bI1[r]; }
#pragma unroll
    for (int off = 1; off < 32; off <<= 1) {
      float od = __shfl_xor(d0, off);
      int oi = __shfl_xor(i0, off);
      if (od < d0 || (od == d0 && oi < i0)) { d0 = od; i0 = oi; }
    }
    if (lanec == 0) {
      int lr = wrow * 32 + 4 * laneh + ((r & 3) + 8 * (r >> 2));
      Md[wcol][lr] = d0;
      Mi[wcol][lr] = i0;
    }
  }
  __syncthreads();
  // final cross-wcol merge: each of the 128 block rows written exactly once
  if (tid < 128) {
    float da = Md[0][tid]; int ia = Mi[0][tid];
    float db = Md[1][tid]; int ib = Mi[1][tid];
    if (db < da || (db == da && ib < ia)) { da = db; ia = ib; }
    bestD[half * NN + panel * 128 + tid] = da;
    bestI[half * NN + panel * 128 + tid] = ia;
  }
}

// --- merge halves, count label matches ---
__global__ __launch_bounds__(256) void combine_kernel(const float* __restrict__ bestD,
                                                      const int* __restrict__ bestI,
                                                      const int* __restrict__ labels,
                                                      int* __restrict__ count) {
  int r = blockIdx.x * 256 + threadIdx.x;
  float d0 = bestD[r];
  int i0 = bestI[r];
  float d1 = bestD[NN + r];
  int i1 = bestI[NN + r];
  int pred = (d1 < d0) ? i1 : i0;  // tie -> half 0 (smaller j) = argmin-first
  bool match = (labels[pred] == labels[r]);
  unsigned long long mb = __ballot(match);
  if ((threadIdx.x & 63) == 0) atomicAdd(count, (int)__popcll(mb));
}

__global__ void finalize_kernel(const int* __restrict__ count, float* __restrict__ out) {
  out[0] = (float)(*count) * (1.0f / 16384.0f);
}

extern "C" void kernel_launch(void* const* d_in, const int* in_sizes, int n_in,
                              void* d_out, int out_size, void* d_ws, size_t ws_size,
                              hipStream_t stream) {
  const float* feat = (const float*)d_in[0];
  const int* labels = (const int*)d_in[1];
  float* out = (float*)d_out;
  char* ws = (char*)d_ws;

  int* count = (int*)ws;                                  // 4 B
  float* sq = (float*)(ws + 1024);                        // 64 KB
  float* bestD = (float*)(ws + 1024 + 65536);             // 128 KB
  int* bestI = (int*)(ws + 1024 + 65536 + 131072);        // 128 KB
  bf16x8* Ph = (bf16x8*)(ws + (1 << 20));                 // 4 MB
  bf16x8* Pl = (bf16x8*)(ws + (6 << 20));                 // 4 MB   (total ~10 MB)

  hipMemsetAsync(count, 0, sizeof(int), stream);
  sq_kernel<<<NN / 4, 256, 0, stream>>>(feat, sq);
  convert_kernel<<<1024, 256, 0, stream>>>(feat, Ph, Pl);
  nn_mfma<<<256, 512, 0, stream>>>(Ph, Pl, sq, bestD, bestI);
  combine_kernel<<<NN / 256, 256, 0, stream>>>(bestD, bestI, labels, count);
  finalize_kernel<<<1, 1, 0, stream>>>(count, out);
}